// Round 6
// baseline (133.679 us; speedup 1.0000x reference)
//
#include <hip/hip_runtime.h>

// uvs [B=16, J=16, M=512, D=256] fp32. j<8 = u (k=j), j>=8 = v (k=j-8).
// gate_u[b,k,m] = (dot(u[b,k,m,:], colsum(v[b,k])) > 0); symmetric for v.
//
// Single cooperative-style kernel; the v half (64 MiB) is held IN REGISTERS
// across two grid-wide barriers so v is fetched from HBM exactly once:
// read u+v once (134 MB) + write outputs (134 MB) = 268 MB total.
//
// R4/R5 failure: cg::grid_group::sync() (non-inlined call) + allocator
// occupancy-chasing spilled the v array to scratch (VGPR_Count 64/96,
// 116-126 us). Fix: fully-inlined manual grid barrier (atomicAdd + spin on a
// ws counter zeroed per launch by hipMemsetAsync) and amdgpu_waves_per_eu(4,4)
// pinning both min AND max waves/EU -> VGPR budget 128, no shrink incentive.
//
// 256 blocks (1/CU) x 1024 threads (16 waves, 4/SIMD). Block (bk,s) owns rows
// [s*256, s*256+256) of u[b,k] and v[b,k]; wave w rows [w*16, w*16+16); lane l
// owns float4 column l. vreg[16] = 64 VGPRs, all indexing statically unrolled.

#define NBLK 256
#define NTHR 1024

typedef float f32x4 __attribute__((ext_vector_type(4)));

// Monotonic grid barrier: counter starts at 0 each launch (memsetAsync);
// barrier k waits for count >= k*NBLK. Release/acquire fences make the
// ws partials visible across XCDs (per-XCD L2s are not coherent).
__device__ __forceinline__ void grid_barrier(unsigned* cnt, unsigned target) {
    __syncthreads();
    if (threadIdx.x == 0) {
        __threadfence();   // release: drain + make prior stores device-visible
        __hip_atomic_fetch_add(cnt, 1u, __ATOMIC_RELEASE, __HIP_MEMORY_SCOPE_AGENT);
        while (__hip_atomic_load(cnt, __ATOMIC_ACQUIRE, __HIP_MEMORY_SCOPE_AGENT) < target)
            __builtin_amdgcn_s_sleep(2);
        __threadfence();   // acquire: invalidate stale cached lines
    }
    __syncthreads();
}

__global__ __launch_bounds__(NTHR)
__attribute__((amdgpu_waves_per_eu(4, 4)))
void k_fused(const f32x4* __restrict__ in,
             f32x4* __restrict__ out,
             f32x4* __restrict__ vpart,
             f32x4* __restrict__ upart,
             unsigned* __restrict__ cnt) {
    const int blk = blockIdx.x;
    const int s   = blk & 1;
    const int bk  = blk >> 1;              // [0,128)
    const int b   = bk >> 3, k = bk & 7;
    const int t   = threadIdx.x;
    const int l   = t & 63;
    const int w   = t >> 6;                // [0,16)

    const size_t vbase = ((size_t)((b * 16 + 8 + k) * 512) + s * 256 + w * 16) * 64 + l;
    const size_t ubase = ((size_t)((b * 16 + k) * 512) + s * 256 + w * 16) * 64 + l;

    __shared__ f32x4 red[NTHR];            // 16 KiB block-reduce buffer

    // ---- Phase A: v chunk -> registers; block-partial column sum ----
    f32x4 vreg[16];
    f32x4 acc = {0.f, 0.f, 0.f, 0.f};
#pragma unroll
    for (int i = 0; i < 16; ++i) {
        vreg[i] = __builtin_nontemporal_load(in + vbase + (size_t)i * 64);
        acc += vreg[i];
    }
    red[t] = acc;
    __syncthreads();
    if (t < 64) {                          // l == t
        f32x4 r = {0.f, 0.f, 0.f, 0.f};
#pragma unroll
        for (int q = 0; q < 16; ++q) r += red[q * 64 + t];
        vpart[(size_t)blk * 64 + t] = r;
    }

    grid_barrier(cnt, NBLK);

    // ---- Phase B: stream u once; gate vs vsum; accumulate usum partial ----
    const f32x4 vs = vpart[(size_t)(bk * 2 + 0) * 64 + l] +
                     vpart[(size_t)(bk * 2 + 1) * 64 + l];
    f32x4 uacc = {0.f, 0.f, 0.f, 0.f};
#pragma unroll 4
    for (int i = 0; i < 16; ++i) {
        f32x4 uv = __builtin_nontemporal_load(in + ubase + (size_t)i * 64);
        uacc += uv;
        float p = uv.x * vs.x + uv.y * vs.y + uv.z * vs.z + uv.w * vs.w;
#pragma unroll
        for (int off = 32; off; off >>= 1) p += __shfl_xor(p, off, 64);
        const float g = (p > 0.f) ? 1.f : 0.f;
        __builtin_nontemporal_store(uv * g, out + ubase + (size_t)i * 64);
    }
    __syncthreads();                       // red[] reuse: phase-A readers done
    red[t] = uacc;
    __syncthreads();
    if (t < 64) {
        f32x4 r = {0.f, 0.f, 0.f, 0.f};
#pragma unroll
        for (int q = 0; q < 16; ++q) r += red[q * 64 + t];
        upart[(size_t)blk * 64 + t] = r;
    }

    grid_barrier(cnt, 2 * NBLK);

    // ---- Phase C: gate register-resident v; store (no v re-read) ----
    const f32x4 us = upart[(size_t)(bk * 2 + 0) * 64 + l] +
                     upart[(size_t)(bk * 2 + 1) * 64 + l];
#pragma unroll
    for (int i = 0; i < 16; ++i) {
        float p = vreg[i].x * us.x + vreg[i].y * us.y +
                  vreg[i].z * us.z + vreg[i].w * us.w;
#pragma unroll
        for (int off = 32; off; off >>= 1) p += __shfl_xor(p, off, 64);
        const float g = (p > 0.f) ? 1.f : 0.f;
        __builtin_nontemporal_store(vreg[i] * g, out + vbase + (size_t)i * 64);
    }
}

extern "C" void kernel_launch(void* const* d_in, const int* in_sizes, int n_in,
                              void* d_out, int out_size, void* d_ws, size_t ws_size,
                              hipStream_t stream) {
    const f32x4* in  = (const f32x4*)d_in[0];
    f32x4*       out = (f32x4*)d_out;
    // ws layout: vpart 256 KiB @ 0, upart 256 KiB @ 256 KiB (fully written
    // before read each call), barrier counter 4 B @ 512 KiB (zeroed below).
    f32x4*    vpart = (f32x4*)d_ws;
    f32x4*    upart = (f32x4*)((char*)d_ws + (256u << 10));
    unsigned* cnt   = (unsigned*)((char*)d_ws + (512u << 10));

    hipMemsetAsync(cnt, 0, sizeof(unsigned), stream);   // replay-safe barrier init

    void* args[] = { (void*)&in, (void*)&out, (void*)&vpart, (void*)&upart, (void*)&cnt };
    hipLaunchCooperativeKernel((void*)k_fused, dim3(NBLK), dim3(NTHR),
                               args, 0, stream);
}

// Round 7
// 100.053 us; speedup vs baseline: 1.3361x; 1.3361x over previous
//
#include <hip/hip_runtime.h>

// uvs [B=16, J=16, M=512, D=256] fp32. j<8 = u (k=j), j>=8 = v (k=j-8).
// gate_u[b,k,m] = (dot(u[b,k,m,:], colsum(v[b,k])) > 0); symmetric for v.
//
// Single cooperative kernel; the v half (64 MiB) stays in the unified
// VGPR/AGPR file across two grid-wide barriers -> v fetched from HBM once.
// Traffic: read u+v once (134 MB) + write outputs (134 MB) = 268 MB.
//
// R4-R6 post-mortem: the v array was parked in AGPRs all along (VGPR_Count +
// array size == budget; no scratch traffic in FETCH/WRITE). The 113-133 us
// came from the grid-sync fences: cg::sync and __threadfence both emit
// agent-scope L2 writeback/invalidate + vmcnt(0) drains per block, which
// serialize the NT streams and nuke L2 at every barrier. This version has NO
// fences: partials go through relaxed AGENT-scope atomic stores/loads
// (coherence-point access, no cache maintenance); the block signals with a
// relaxed atomic add after draining only its own stores (s_waitcnt vmcnt(0)).
//
// 256 blocks (1/CU) x 1024 threads (16 waves). Block (bk,s) owns rows
// [s*256, s*256+256) of u[b,k] and v[b,k]; wave w rows [w*16..w*16+16);
// lane l owns float4 column l. vreg[16] statically indexed.

#define NBLK 256
#define NTHR 1024

typedef float f32x4 __attribute__((ext_vector_type(4)));

__device__ __forceinline__ void part_store(float* p, f32x4 v) {
    __hip_atomic_store(p + 0, v.x, __ATOMIC_RELAXED, __HIP_MEMORY_SCOPE_AGENT);
    __hip_atomic_store(p + 1, v.y, __ATOMIC_RELAXED, __HIP_MEMORY_SCOPE_AGENT);
    __hip_atomic_store(p + 2, v.z, __ATOMIC_RELAXED, __HIP_MEMORY_SCOPE_AGENT);
    __hip_atomic_store(p + 3, v.w, __ATOMIC_RELAXED, __HIP_MEMORY_SCOPE_AGENT);
}

__device__ __forceinline__ f32x4 part_load(const float* p) {
    f32x4 r;
    r.x = __hip_atomic_load(p + 0, __ATOMIC_RELAXED, __HIP_MEMORY_SCOPE_AGENT);
    r.y = __hip_atomic_load(p + 1, __ATOMIC_RELAXED, __HIP_MEMORY_SCOPE_AGENT);
    r.z = __hip_atomic_load(p + 2, __ATOMIC_RELAXED, __HIP_MEMORY_SCOPE_AGENT);
    r.w = __hip_atomic_load(p + 3, __ATOMIC_RELAXED, __HIP_MEMORY_SCOPE_AGENT);
    return r;
}

// Fence-free monotonic grid barrier. Counter zeroed per launch (memsetAsync);
// barrier k waits for count >= k*NBLK. The vmcnt(0) drains only this wave's
// outstanding stores (the block's partial stores were issued by wave 0's
// threads... all waves sync first, and each thread's atomic stores are
// already at the coherence point once its own vmcnt retires; __syncthreads
// waits vmcnt per-wave before s_barrier, so by the time thread 0 runs, all
// the block's partial stores are globally visible).
__device__ __forceinline__ void grid_barrier(unsigned* cnt, unsigned target) {
    __syncthreads();
    if (threadIdx.x == 0) {
        __hip_atomic_fetch_add(cnt, 1u, __ATOMIC_RELAXED, __HIP_MEMORY_SCOPE_AGENT);
        while (__hip_atomic_load(cnt, __ATOMIC_RELAXED, __HIP_MEMORY_SCOPE_AGENT) < target)
            __builtin_amdgcn_s_sleep(4);
    }
    __syncthreads();
}

__global__ __launch_bounds__(NTHR)
void k_fused(const f32x4* __restrict__ in,
             f32x4* __restrict__ out,
             float* __restrict__ vpart,
             float* __restrict__ upart,
             unsigned* __restrict__ cnt) {
    const int blk = blockIdx.x;
    const int s   = blk & 1;
    const int bk  = blk >> 1;              // [0,128)
    const int b   = bk >> 3, k = bk & 7;
    const int t   = threadIdx.x;
    const int l   = t & 63;
    const int w   = t >> 6;                // [0,16)

    const size_t vbase = ((size_t)((b * 16 + 8 + k) * 512) + s * 256 + w * 16) * 64 + l;
    const size_t ubase = ((size_t)((b * 16 + k) * 512) + s * 256 + w * 16) * 64 + l;

    __shared__ f32x4 red[NTHR];            // 16 KiB block-reduce buffer

    // ---- Phase A: v chunk -> registers (AGPR parking ok); partial colsum ----
    f32x4 vreg[16];
    f32x4 acc = {0.f, 0.f, 0.f, 0.f};
#pragma unroll
    for (int i = 0; i < 16; ++i) {
        vreg[i] = __builtin_nontemporal_load(in + vbase + (size_t)i * 64);
        acc += vreg[i];
    }
    red[t] = acc;
    __syncthreads();
    if (t < 64) {                          // l == t
        f32x4 r = {0.f, 0.f, 0.f, 0.f};
#pragma unroll
        for (int q = 0; q < 16; ++q) r += red[q * 64 + t];
        part_store(vpart + (size_t)(blk * 64 + t) * 4, r);
    }

    grid_barrier(cnt, NBLK);

    // ---- Phase B: stream u once; gate vs vsum; accumulate usum partial ----
    const f32x4 vs = part_load(vpart + (size_t)((bk * 2 + 0) * 64 + l) * 4) +
                     part_load(vpart + (size_t)((bk * 2 + 1) * 64 + l) * 4);
    f32x4 uacc = {0.f, 0.f, 0.f, 0.f};
#pragma unroll 4
    for (int i = 0; i < 16; ++i) {
        f32x4 uv = __builtin_nontemporal_load(in + ubase + (size_t)i * 64);
        uacc += uv;
        float p = uv.x * vs.x + uv.y * vs.y + uv.z * vs.z + uv.w * vs.w;
#pragma unroll
        for (int off = 32; off; off >>= 1) p += __shfl_xor(p, off, 64);
        const float g = (p > 0.f) ? 1.f : 0.f;
        __builtin_nontemporal_store(uv * g, out + ubase + (size_t)i * 64);
    }
    __syncthreads();                       // red[] reuse: phase-A readers done
    red[t] = uacc;
    __syncthreads();
    if (t < 64) {
        f32x4 r = {0.f, 0.f, 0.f, 0.f};
#pragma unroll
        for (int q = 0; q < 16; ++q) r += red[q * 64 + t];
        part_store(upart + (size_t)(blk * 64 + t) * 4, r);
    }

    grid_barrier(cnt, 2 * NBLK);

    // ---- Phase C: gate register-resident v; store (no v re-read) ----
    const f32x4 us = part_load(upart + (size_t)((bk * 2 + 0) * 64 + l) * 4) +
                     part_load(upart + (size_t)((bk * 2 + 1) * 64 + l) * 4);
#pragma unroll
    for (int i = 0; i < 16; ++i) {
        float p = vreg[i].x * us.x + vreg[i].y * us.y +
                  vreg[i].z * us.z + vreg[i].w * us.w;
#pragma unroll
        for (int off = 32; off; off >>= 1) p += __shfl_xor(p, off, 64);
        const float g = (p > 0.f) ? 1.f : 0.f;
        __builtin_nontemporal_store(vreg[i] * g, out + vbase + (size_t)i * 64);
    }
}

extern "C" void kernel_launch(void* const* d_in, const int* in_sizes, int n_in,
                              void* d_out, int out_size, void* d_ws, size_t ws_size,
                              hipStream_t stream) {
    const f32x4* in  = (const f32x4*)d_in[0];
    f32x4*       out = (f32x4*)d_out;
    // ws layout: vpart 256 KiB @ 0, upart 256 KiB @ 256 KiB (single-writer
    // slots, fully written before read each call), counter 4 B @ 512 KiB.
    float*    vpart = (float*)d_ws;
    float*    upart = (float*)((char*)d_ws + (256u << 10));
    unsigned* cnt   = (unsigned*)((char*)d_ws + (512u << 10));

    hipMemsetAsync(cnt, 0, sizeof(unsigned), stream);   // replay-safe barrier init

    void* args[] = { (void*)&in, (void*)&out, (void*)&vpart, (void*)&upart, (void*)&cnt };
    hipLaunchCooperativeKernel((void*)k_fused, dim3(NBLK), dim3(NTHR),
                               args, 0, stream);
}

// Round 8
// 59.865 us; speedup vs baseline: 2.2330x; 1.6713x over previous
//
#include <hip/hip_runtime.h>
#include <hip/hip_bf16.h>

// uvs [B=16, J=16, M=512, D=256] fp32. j<8 = u (k=j), j>=8 = v (k=j-8).
// gate_u[b,k,m] = (dot(u[b,k,m,:], colsum(v[b,k])) > 0); symmetric for v.
//
// 3-kernel structure (R3, 64.1 us) — fusion attempts R4-R7 all lost to
// grid-sync costs; reverted. This round: same structure/traffic (335 MB),
// 512-thread blocks -> 32 waves/CU (was 16) to hide DS-reduce + mem latency.
//   K1: v -> vsum partials                      (read 67 MB)
//   K2: u -> gated-u + usum partials            (read 67, write 67)
//   K3: v re-read -> gated-v                    (read 67, write 67)
// Deterministic tree reductions via d_ws partials (1 MiB + 1 MiB, proven
// size); no atomics (gate signs must be replay-stable).

#define B_   16
#define K_   8
#define M_   512
#define D4_  64          // 256 floats = 64 float4 per row
#define S_   8           // m-splits -> 1024 blocks per pass
#define NT_  512         // threads/block = 8 waves

typedef float f32x4 __attribute__((ext_vector_type(4)));

// Block-level column-sum reduce: 512 threads -> 64 lanes, then store.
__device__ __forceinline__ void block_colsum_store(f32x4 acc, int t,
                                                   f32x4* red,
                                                   f32x4* __restrict__ dst) {
    red[t] = acc;
    __syncthreads();
    if (t < 64) {
        f32x4 r = {0.f, 0.f, 0.f, 0.f};
#pragma unroll
        for (int q = 0; q < 8; ++q) r += red[q * 64 + t];
        dst[t] = r;
    }
}

// --------------------------------------------------------------------------
// K1: partial column sums of the v half. Grid 1024 = (b,k) x s.
// Block sums rows [s*64, s*64+64) of v[b,k]; wave w rows [w*8, w*8+8).
// --------------------------------------------------------------------------
__global__ __launch_bounds__(NT_) void k_vsum(const f32x4* __restrict__ in,
                                              f32x4* __restrict__ vpart) {
    const int blk = blockIdx.x;
    const int s   = blk & (S_ - 1);
    const int bk  = blk >> 3;                 // [0,128)
    const int b   = bk >> 3, k = bk & 7;
    const int t   = threadIdx.x;
    const int l   = t & 63;
    const int w   = t >> 6;                   // [0,8)

    const f32x4* base = in + ((size_t)((b * 16 + 8 + k) * M_) + s * 64 + w * 8) * D4_ + l;

    f32x4 acc = {0.f, 0.f, 0.f, 0.f};
#pragma unroll
    for (int i = 0; i < 8; ++i) acc += base[(size_t)i * D4_];

    __shared__ f32x4 red[NT_];
    block_colsum_store(acc, t, red, vpart + (size_t)blk * 64);
}

// --------------------------------------------------------------------------
// K2: u pass. Gather vsum (8 partials) -> registers; stream 64 rows of u:
// load -> dot -> 6-step shfl_xor wave reduce -> gate -> NT store gated u.
// Accumulate block-partial usum -> upart.
// --------------------------------------------------------------------------
__global__ __launch_bounds__(NT_) void k_upass(const f32x4* __restrict__ in,
                                               const f32x4* __restrict__ vpart,
                                               f32x4* __restrict__ upart,
                                               f32x4* __restrict__ out) {
    const int blk = blockIdx.x;
    const int s   = blk & (S_ - 1);
    const int bk  = blk >> 3;
    const int b   = bk >> 3, k = bk & 7;
    const int t   = threadIdx.x;
    const int l   = t & 63;
    const int w   = t >> 6;

    f32x4 vs = {0.f, 0.f, 0.f, 0.f};
#pragma unroll
    for (int q = 0; q < S_; ++q) vs += vpart[(size_t)(bk * S_ + q) * 64 + l];

    const size_t rowbase = ((size_t)((b * 16 + k) * M_) + s * 64 + w * 8) * D4_ + l;
    const f32x4* inb  = in + rowbase;
    f32x4*       outb = (f32x4*)(out + rowbase);

    f32x4 uacc = {0.f, 0.f, 0.f, 0.f};
#pragma unroll
    for (int i = 0; i < 8; ++i) {
        f32x4 uv = inb[(size_t)i * D4_];
        uacc += uv;
        float p = uv.x * vs.x + uv.y * vs.y + uv.z * vs.z + uv.w * vs.w;
#pragma unroll
        for (int off = 32; off; off >>= 1) p += __shfl_xor(p, off, 64);
        const float g = (p > 0.f) ? 1.f : 0.f;
        __builtin_nontemporal_store(uv * g, outb + (size_t)i * D4_);
    }

    __shared__ f32x4 red[NT_];
    block_colsum_store(uacc, t, red, upart + (size_t)blk * 64);
}

// --------------------------------------------------------------------------
// K3: v pass. Gather usum -> registers; re-read v, gate, NT store gated v.
// --------------------------------------------------------------------------
__global__ __launch_bounds__(NT_) void k_vpass(const f32x4* __restrict__ in,
                                               const f32x4* __restrict__ upart,
                                               f32x4* __restrict__ out) {
    const int blk = blockIdx.x;
    const int s   = blk & (S_ - 1);
    const int bk  = blk >> 3;
    const int b   = bk >> 3, k = bk & 7;
    const int t   = threadIdx.x;
    const int l   = t & 63;
    const int w   = t >> 6;

    f32x4 us = {0.f, 0.f, 0.f, 0.f};
#pragma unroll
    for (int q = 0; q < S_; ++q) us += upart[(size_t)(bk * S_ + q) * 64 + l];

    const size_t rowbase = ((size_t)((b * 16 + 8 + k) * M_) + s * 64 + w * 8) * D4_ + l;
    const f32x4* inb  = in + rowbase;
    f32x4*       outb = (f32x4*)(out + rowbase);

#pragma unroll
    for (int i = 0; i < 8; ++i) {
        f32x4 vv = inb[(size_t)i * D4_];
        float p = vv.x * us.x + vv.y * us.y + vv.z * us.z + vv.w * us.w;
#pragma unroll
        for (int off = 32; off; off >>= 1) p += __shfl_xor(p, off, 64);
        const float g = (p > 0.f) ? 1.f : 0.f;
        __builtin_nontemporal_store(vv * g, outb + (size_t)i * D4_);
    }
}

extern "C" void kernel_launch(void* const* d_in, const int* in_sizes, int n_in,
                              void* d_out, int out_size, void* d_ws, size_t ws_size,
                              hipStream_t stream) {
    const f32x4* in  = (const f32x4*)d_in[0];
    f32x4*       out = (f32x4*)d_out;
    // ws: vpart 1 MiB @ 0, upart 1 MiB @ 1 MiB (proven size R3).
    // Both fully written before read each call; no atomics anywhere.
    f32x4* vpart = (f32x4*)d_ws;
    f32x4* upart = (f32x4*)((char*)d_ws + (1u << 20));

    const int grid = B_ * K_ * S_;   // 1024
    k_vsum <<<grid, NT_, 0, stream>>>(in, vpart);
    k_upass<<<grid, NT_, 0, stream>>>(in, vpart, upart, out);
    k_vpass<<<grid, NT_, 0, stream>>>(in, upart, out);
}